// Round 14
// baseline (494.378 us; speedup 1.0000x reference)
//
#include <hip/hip_runtime.h>
#include <hip/hip_bf16.h>
#include <cstdint>

#define B_N 65536
#define F_N 64
#define L_N 32
#define E_N 512
// K = F*L = 2048, k-octs = 256

typedef short bf16x8 __attribute__((ext_vector_type(8)));
typedef float f32x4 __attribute__((ext_vector_type(4)));

// GELU via A&S 7.1.27 erf (|eps| <= 5e-4): 1 transcendental (rcp), no exp.
__device__ __forceinline__ float gelu_fast(float v) {
  float z = fabsf(v) * 0.7071067811865476f;
  float p = fmaf(z, fmaf(z, fmaf(z, fmaf(z, 0.078108f, 0.000972f),
                                 0.230389f), 0.278393f), 1.0f);
  float p2 = p * p;
  float p4 = p2 * p2;
  float er = 1.0f - __builtin_amdgcn_rcpf(p4);  // erf(|z|)
  float half_er = copysignf(0.5f * er, v);
  return v * (0.5f + half_er);
}

// exact GELU (fallback kernel only)
__device__ __forceinline__ float gelu_exact(float v) {
  float z  = v * 0.7071067811865476f;
  float az = fabsf(z);
  float t  = __builtin_amdgcn_rcpf(fmaf(0.3275911f, az, 1.0f));
  float p  = t * fmaf(t, fmaf(t, fmaf(t, fmaf(t, 1.061405429f, -1.453152027f),
                                      1.421413741f), -0.284496736f), 0.254829592f);
  float e    = __expf(-z * z);
  float erfa = fmaf(-p, e, 1.0f);
  float er   = (z < 0.0f) ? -erfa : erfa;
  return v * fmaf(0.5f, er, 0.5f);
}

// ---------------- merged prep: wb2/out_tail (bb 0-1), W1T (bb 2-17),
// ---------------- W2T w-folded bf16 (bb 18-273). One launch. ---------------
// R6: W1T k-axis PERMUTED to interleave sin/cos rows of the same frequency:
//   fragment element e = 2d   -> W1 row (quad*4 + d)        [sin freq q*4+d]
//   fragment element e = 2d+1 -> W1 row (16 + quad*4 + d)   [cos freq q*4+d]
__global__ __launch_bounds__(256) void k_pre(const float* __restrict__ w_raw,
                                             const float* __restrict__ b2,
                                             const float* __restrict__ W1,
                                             const float* __restrict__ W2,
                                             float* __restrict__ wb2,
                                             float* __restrict__ out_tail,
                                             uint4* __restrict__ W1T,
                                             uint4* __restrict__ W2T) {
  __shared__ float ls[64 * 65];
  int bb = blockIdx.x, tid = threadIdx.x;
  // redundant per-thread softmax (64-wide, cheap)
  float m = -1e30f;
  for (int i = 0; i < F_N; i++) m = fmaxf(m, w_raw[i]);
  float s = 0.f;
  for (int i = 0; i < F_N; i++) s += expf(w_raw[i] - m);
  float inv_s = 1.0f / s;

  if (bb < 2) {
    int e = bb * 256 + tid;
    float a = 0.f;
    for (int f = 0; f < F_N; f++)
      a = fmaf(expf(w_raw[f] - m) * inv_s, b2[f * E_N + e], a);
    wb2[e] = a;
    if (bb == 0 && tid < F_N) out_tail[tid] = expf(w_raw[tid] - m) * inv_s;
  } else if (bb < 18) {
    // W1T[(f*2+jt)*64+lane] = 8 bf16, k-permuted (see header comment)
    int f = (bb - 2) * 4 + (tid >> 6);
    int lane = tid & 63, quad = lane >> 4, r16 = lane & 15;
#pragma unroll
    for (int jt = 0; jt < 2; jt++) {
      union { __hip_bfloat162 p[4]; uint4 u; } pk;
#pragma unroll
      for (int d = 0; d < 4; d++) {
        float lo = W1[f * 1024 + (quad * 4 + d) * 32 + jt * 16 + r16];        // sin
        float hi = W1[f * 1024 + (16 + quad * 4 + d) * 32 + jt * 16 + r16];   // cos
        pk.p[d] = __float22bfloat162_rn(make_float2(lo, hi));
      }
      W1T[(f * 2 + jt) * 64 + lane] = pk.u;
    }
  } else {
    // W2T blocked [k_oct][e][8], rows pre-scaled by softmax w[f=k>>5]
    int blk = bb - 18;
    int kt = blk >> 3, et = blk & 7;
    int k0 = kt * 64, e0 = et * 64;
#pragma unroll
    for (int i = 0; i < 16; i++) {
      int idx = i * 256 + tid;
      int r = idx >> 6, c = idx & 63;
      float wrow = expf(w_raw[(k0 + r) >> 5] - m) * inv_s;
      ls[r * 65 + c] = W2[(size_t)(k0 + r) * E_N + e0 + c] * wrow;
    }
    __syncthreads();
#pragma unroll
    for (int i = 0; i < 2; i++) {
      int t = i * 256 + tid;
      int ko = t >> 6, e = t & 63;
      union { __hip_bfloat162 p[4]; uint4 u; } pk;
#pragma unroll
      for (int d = 0; d < 4; d++)
        pk.p[d] = __float22bfloat162_rn(make_float2(ls[(ko * 8 + 2 * d) * 65 + e],
                                                    ls[(ko * 8 + 2 * d + 1) * 65 + e]));
      W2T[(size_t)(kt * 8 + ko) * E_N + e0 + e] = pk.u;
    }
  }
}

// ---------------- enc per-chunk state (persistent across its bt iters) -----
struct EncSt {
  bf16x8 a0, a1;       // W1T fragments
  f32x4 c0, c1;        // b1 seed
  float gv[8], bev[8]; // gamma/beta
  int f, swz;
};

__device__ __forceinline__ void enc_load(EncSt& st, int c, int waven, int quad,
                                         int r16, int lane,
                                         const uint4* __restrict__ W1T,
                                         const float* __restrict__ b1,
                                         const float* __restrict__ gamma,
                                         const float* __restrict__ beta) {
  int f = c * 8 + waven;
  st.f = f;
  st.swz = f & 31;
  st.a0 = __builtin_bit_cast(bf16x8, W1T[(f * 2 + 0) * 64 + lane]);
  st.a1 = __builtin_bit_cast(bf16x8, W1T[(f * 2 + 1) * 64 + lane]);
#pragma unroll
  for (int rr = 0; rr < 4; rr++) {
    st.c0[rr] = b1[f * 32 + quad * 4 + rr];
    st.c1[rr] = b1[f * 32 + 16 + quad * 4 + rr];
  }
#pragma unroll
  for (int q = 0; q < 8; q++) {
    int idx = f * 32 + (q >> 2) * 16 + quad * 4 + (q & 3);
    st.gv[q] = gamma[idx];
    st.bev[q] = beta[idx];
  }
}

// ---- one bt iter of enc: 16 batch rows of feature st.f -> hwb -------------
// xs XOR-swizzled: x(f,b) at xs[f*64 + (b ^ (f&31))].
// sincos: 1 v_sin + 1 v_cos + 3-step angle-doubling (matches permuted W1T).
__device__ __forceinline__ void enc_bt(const EncSt& st, int bt, int waven,
                                       int quad, int r16, const float* xs,
                                       uint4* hwb, float c_t) {
  float x = xs[st.f * 64 + ((bt * 16 + r16) ^ st.swz)];
  float y = x * c_t;
  y = y - floorf(y);
  float sv = __builtin_amdgcn_sinf(y);
  float cv = __builtin_amdgcn_cosf(y);
  float v[8];
  v[0] = sv; v[1] = cv;
#pragma unroll
  for (int d = 1; d < 4; d++) {
    float c2 = cv + cv;
    float sn = c2 * sv;                 // sin(2t) = 2 sin t cos t
    float cn = fmaf(c2, cv, -1.0f);     // cos(2t) = 2 cos^2 t - 1
    v[2 * d] = sn; v[2 * d + 1] = cn;
    sv = sn; cv = cn;
  }
  union { __hip_bfloat162 p[4]; bf16x8 r; } pk;
#pragma unroll
  for (int d = 0; d < 4; d++)
    pk.p[d] = __float22bfloat162_rn(make_float2(v[2 * d], v[2 * d + 1]));
  f32x4 e0 = __builtin_amdgcn_mfma_f32_16x16x32_bf16(st.a0, pk.r, st.c0, 0, 0, 0);
  f32x4 e1 = __builtin_amdgcn_mfma_f32_16x16x32_bf16(st.a1, pk.r, st.c1, 0, 0, 0);
  float h[8];
#pragma unroll
  for (int rr = 0; rr < 4; rr++) { h[rr] = e0[rr]; h[4 + rr] = e1[rr]; }
  float sum = 0.f;
#pragma unroll
  for (int q = 0; q < 8; q++) sum += h[q];
  sum += __shfl_xor(sum, 16);
  sum += __shfl_xor(sum, 32);
  float mu = sum * (1.0f / 32.0f);
  float var = 0.f;
#pragma unroll
  for (int q = 0; q < 8; q++) { h[q] -= mu; var = fmaf(h[q], h[q], var); }
  var += __shfl_xor(var, 16);
  var += __shfl_xor(var, 32);
  float rs = __builtin_amdgcn_rsqf(fmaf(var, (1.0f / 32.0f), 1e-5f));
#pragma unroll
  for (int q = 0; q < 8; q++) {
    float hn = fmaf(h[q] * rs, st.gv[q], st.bev[q]);
    h[q] = gelu_fast(hn);  // w[f] folded into W2T
  }
  int b_local = bt * 16 + r16;
#pragma unroll
  for (int jt = 0; jt < 2; jt++) {
    union { __hip_bfloat162 p[2]; uint2 u; } pw;
    pw.p[0] = __float22bfloat162_rn(make_float2(h[jt * 4 + 0], h[jt * 4 + 1]));
    pw.p[1] = __float22bfloat162_rn(make_float2(h[jt * 4 + 2], h[jt * 4 + 3]));
    int ko_local = waven * 4 + jt * 2 + (quad >> 1);
    *(uint2*)((char*)hwb + ((size_t)(ko_local * 64 + b_local) * 16 +
                            (quad & 1) * 8)) = pw.u;
  }
}

// ---- fused chunk: gemm(cg from hw_rd) interleaved with enc(ce -> hw_wr) ---
// R11: retry of R7's intra-wave MFMA||VALU interleave, now with acc[2][4]
// (32 AGPR, 16-wave M-split) instead of acc[4][4] (64 AGPR). R7/R8 spilled
// because acc64+arch64 = exactly the 128 cap at 4 waves/SIMD; halving acc
// gives ~32 regs of slack for EncSt to live across the MFMA cluster.
// One enc bt-iter is slotted after every 4 gemm s-iters (2 bt per chunk).
template <bool ENC>
__device__ __forceinline__ void fused_chunk(int cg, int ce, int waven, int wavem,
                                            int lane, int quad, int r16,
                                            int n_base, const uint4* hw_rd,
                                            uint4* hw_wr, const float* xs,
                                            const uint4* __restrict__ W1T,
                                            const uint4* __restrict__ W2T,
                                            const float* __restrict__ b1,
                                            const float* __restrict__ gamma,
                                            const float* __restrict__ beta,
                                            float c_t, f32x4 (&acc)[2][4]) {
  EncSt st;
  if (ENC) enc_load(st, ce, waven, quad, r16, lane, W1T, b1, gamma, beta);
#pragma unroll
  for (int s = 0; s < 8; s++) {
    bf16x8 af[2], bfr[4];
#pragma unroll
    for (int nt = 0; nt < 4; nt++)
      bfr[nt] = __builtin_bit_cast(
          bf16x8,
          W2T[(size_t)(cg * 32 + s * 4 + quad) * E_N + n_base + nt * 16 + r16]);
#pragma unroll
    for (int mti = 0; mti < 2; mti++)
      af[mti] = __builtin_bit_cast(
          bf16x8, hw_rd[(s * 4 + quad) * 64 + (wavem * 2 + mti) * 16 + r16]);
#pragma unroll
    for (int mti = 0; mti < 2; mti++)
#pragma unroll
      for (int nt = 0; nt < 4; nt++)
        acc[mti][nt] = __builtin_amdgcn_mfma_f32_16x16x32_bf16(af[mti], bfr[nt],
                                                               acc[mti][nt], 0, 0, 0);
    if (ENC && ((s & 3) == 3))
      enc_bt(st, wavem * 2 + (s >> 2), waven, quad, r16, xs, hw_wr, c_t);
  }
}

// ---------------- FUSED, software-pipelined -------------------------------
// R5: LDS = 16384(xs) + 2*32768(hw) = 81920 B.
// R6: nontemporal out-stores/bf-loads keep W2T (2MB) resident in each XCD L2.
// R11: 1024-thread block, 16 waves. Wave w: waven=w&7 -> n_base, wavem=w>>3
// -> row half (rows wavem*32..+31, bt iters wavem*2..+1). acc[2][4]=32 AGPR.
// 1 block/CU x 16 waves = 4 waves/SIMD (same occupancy as R10's 2x8).
// The intra-wave gemm||enc interleave (fused_chunk) now fits the 128-reg cap.
__global__ __launch_bounds__(1024, 4) void k_fused(const float* __restrict__ bf,
                                                   const uint4* __restrict__ W1T,
                                                   const float* __restrict__ b1,
                                                   const float* __restrict__ gamma,
                                                   const float* __restrict__ beta,
                                                   const uint4* __restrict__ W2T,
                                                   const float* __restrict__ wb2,
                                                   float* __restrict__ out) {
  __shared__ float xs[64 * 64];     // x transposed [f][b^swz], XOR-swizzled
  __shared__ uint4 hwA[32 * 64];    // Hw chunk buffers (32 KB each)
  __shared__ uint4 hwB[32 * 64];
  int tid = threadIdx.x;
  int b0 = blockIdx.x * 64;
#pragma unroll
  for (int i = 0; i < 4; i++) {
    int idx = i * 1024 + tid;
    int f = idx & 63, b = idx >> 6;
    xs[f * 64 + (b ^ (f & 31))] =
        __builtin_nontemporal_load(bf + (size_t)b0 * F_N + idx);
  }
  int wave = tid >> 6, lane = tid & 63;
  int waven = wave & 7, wavem = wave >> 3;
  int quad = lane >> 4, r16 = lane & 15;
  // base angle scale: freq idx quad*4 -> 0.1 * 2^(4*quad) / (2*pi)
  float c_t = 0.015915494309189535f;
  if (quad & 1) c_t *= 16.0f;
  if (quad & 2) c_t *= 256.0f;
  int n_base = waven * 64;

  f32x4 acc[2][4];
  f32x4 zero = {0.f, 0.f, 0.f, 0.f};
#pragma unroll
  for (int i = 0; i < 2; i++)
#pragma unroll
    for (int j = 0; j < 4; j++) acc[i][j] = zero;

  __syncthreads();  // xs visible
  {                 // prologue: enc chunk 0 -> A (this wave's 2 bt iters)
    EncSt st0;
    enc_load(st0, 0, waven, quad, r16, lane, W1T, b1, gamma, beta);
#pragma unroll
    for (int bti = 0; bti < 2; bti++)
      enc_bt(st0, wavem * 2 + bti, waven, quad, r16, xs, hwA, c_t);
  }
  __syncthreads();  // hwA visible

  for (int cc = 0; cc < 4; ++cc) {
    // gemm(2cc, A) interleaved with enc(2cc+1 -> B)
    fused_chunk<true>(cc * 2, cc * 2 + 1, waven, wavem, lane, quad, r16, n_base,
                      hwA, hwB, xs, W1T, W2T, b1, gamma, beta, c_t, acc);
    __syncthreads();  // hwB visible; hwA reads done
    if (cc < 3) {
      // gemm(2cc+1, B) interleaved with enc(2cc+2 -> A)
      fused_chunk<true>(cc * 2 + 1, cc * 2 + 2, waven, wavem, lane, quad, r16,
                        n_base, hwB, hwA, xs, W1T, W2T, b1, gamma, beta, c_t,
                        acc);
      __syncthreads();
    } else {
      // last chunk: gemm only, straight to epilogue
      fused_chunk<false>(7, -1, waven, wavem, lane, quad, r16, n_base, hwB,
                         hwA, xs, W1T, W2T, b1, gamma, beta, c_t, acc);
    }
  }

  // epilogue: C/D layout col=n (r16), row=m (quad*4+rr); add wb2 bias.
  // nt innermost: two 64B halves of each 128B line back-to-back; nontemporal.
  float biasv[4];
#pragma unroll
  for (int nt = 0; nt < 4; nt++) biasv[nt] = wb2[n_base + nt * 16 + r16];
#pragma unroll
  for (int mti = 0; mti < 2; mti++) {
#pragma unroll
    for (int rr = 0; rr < 4; rr++) {
      size_t m = (size_t)b0 + (wavem * 2 + mti) * 16 + quad * 4 + rr;
      float* orow = out + m * E_N + n_base + r16;
#pragma unroll
      for (int nt = 0; nt < 4; nt++)
        __builtin_nontemporal_store(acc[mti][nt][rr] + biasv[nt], &orow[nt * 16]);
    }
  }
}

// ---------------- correctness fallback if ws_size too small ----------------
__global__ __launch_bounds__(64) void k_naive(const float* __restrict__ bf,
                                              const float* __restrict__ w_raw,
                                              const float* __restrict__ W1,
                                              const float* __restrict__ b1,
                                              const float* __restrict__ gamma,
                                              const float* __restrict__ beta,
                                              const float* __restrict__ W2,
                                              const float* __restrict__ b2,
                                              float* __restrict__ out) {
  int b = blockIdx.x;
  int lane = threadIdx.x;
  float m = -1e30f;
  for (int i = 0; i < F_N; i++) m = fmaxf(m, w_raw[i]);
  float s = 0.f;
  for (int i = 0; i < F_N; i++) s += expf(w_raw[i] - m);
  float inv_s = 1.0f / s;
  float acc[8];
#pragma unroll
  for (int r = 0; r < 8; r++) acc[r] = 0.f;
  __shared__ float hs[32];
  for (int f = 0; f < F_N; f++) {
    float wf = expf(w_raw[f] - m) * inv_s;
    __syncthreads();
    if (lane < 32) {
      float x = bf[(size_t)b * F_N + f];
      float t = x * 0.015915494309189535f;
      float h = b1[f * 32 + lane];
#pragma unroll
      for (int i = 0; i < 16; i++) {
        float y = t - floorf(t);
        h = fmaf(__builtin_amdgcn_sinf(y), W1[f * 1024 + i * 32 + lane], h);
        h = fmaf(__builtin_amdgcn_cosf(y), W1[f * 1024 + 512 + i * 32 + lane], h);
        t = t + t;
      }
      float sum = h;
#pragma unroll
      for (int msk = 1; msk < 32; msk <<= 1) sum += __shfl_xor(sum, msk, 64);
      float mu = sum * (1.0f / 32.0f);
      float d = h - mu;
      float sq = d * d;
#pragma unroll
      for (int msk = 1; msk < 32; msk <<= 1) sq += __shfl_xor(sq, msk, 64);
      float rs = __builtin_amdgcn_rsqf(fmaf(sq, (1.0f / 32.0f), 1e-5f));
      float hn = fmaf(d * rs, gamma[f * 32 + lane], beta[f * 32 + lane]);
      hs[lane] = gelu_exact(hn) * wf;
    }
    __syncthreads();
#pragma unroll
    for (int r = 0; r < 8; r++) {
      int e = r * 64 + lane;
      float a = fmaf(wf, b2[f * E_N + e], acc[r]);
      for (int j = 0; j < 32; j++)
        a = fmaf(hs[j], W2[(size_t)(f * 32 + j) * E_N + e], a);
      acc[r] = a;
    }
  }
#pragma unroll
  for (int r = 0; r < 8; r++) out[(size_t)b * E_N + r * 64 + lane] = acc[r];
  if (b == 0) out[(size_t)B_N * E_N + lane] = expf(w_raw[lane] - m) * inv_s;
}

extern "C" void kernel_launch(void* const* d_in, const int* in_sizes, int n_in,
                              void* d_out, int out_size, void* d_ws, size_t ws_size,
                              hipStream_t stream) {
  const float* bf    = (const float*)d_in[0];
  const float* w_raw = (const float*)d_in[1];
  const float* W1    = (const float*)d_in[2];
  const float* b1    = (const float*)d_in[3];
  const float* gamma = (const float*)d_in[4];
  const float* beta  = (const float*)d_in[5];
  const float* W2    = (const float*)d_in[6];
  const float* b2    = (const float*)d_in[7];
  float* out = (float*)d_out;

  const size_t W2T_BYTES = (size_t)256 * E_N * 16;  // 2 MB
  const size_t W_OFF     = W2T_BYTES;
  const size_t WB2_OFF   = W_OFF + 256;
  const size_t W1T_OFF   = WB2_OFF + 4096;
  const size_t NEED      = W1T_OFF + 131072;

  if (ws_size < NEED) {  // deterministic fallback (correctness insurance)
    k_naive<<<B_N, 64, 0, stream>>>(bf, w_raw, W1, b1, gamma, beta, W2, b2, out);
    return;
  }
  char* ws = (char*)d_ws;
  uint4* W2T = (uint4*)ws;
  float* wb2 = (float*)(ws + WB2_OFF);
  uint4* W1T = (uint4*)(ws + W1T_OFF);

  k_pre<<<274, 256, 0, stream>>>(w_raw, b2, W1, W2, wb2,
                                 out + (size_t)B_N * E_N, W1T, W2T);
  k_fused<<<B_N / 64, 1024, 0, stream>>>(bf, W1T, b1, gamma, beta, W2T, wb2, out);
}

// Round 15
// 328.549 us; speedup vs baseline: 1.5047x; 1.5047x over previous
//
#include <hip/hip_runtime.h>
#include <hip/hip_bf16.h>
#include <cstdint>

#define B_N 65536
#define F_N 64
#define L_N 32
#define E_N 512
// K = F*L = 2048, k-octs = 256

typedef short bf16x8 __attribute__((ext_vector_type(8)));
typedef float f32x4 __attribute__((ext_vector_type(4)));

// GELU via A&S 7.1.27 erf (|eps| <= 5e-4): 1 transcendental (rcp), no exp.
__device__ __forceinline__ float gelu_fast(float v) {
  float z = fabsf(v) * 0.7071067811865476f;
  float p = fmaf(z, fmaf(z, fmaf(z, fmaf(z, 0.078108f, 0.000972f),
                                 0.230389f), 0.278393f), 1.0f);
  float p2 = p * p;
  float p4 = p2 * p2;
  float er = 1.0f - __builtin_amdgcn_rcpf(p4);  // erf(|z|)
  float half_er = copysignf(0.5f * er, v);
  return v * (0.5f + half_er);
}

// exact GELU (fallback kernel only)
__device__ __forceinline__ float gelu_exact(float v) {
  float z  = v * 0.7071067811865476f;
  float az = fabsf(z);
  float t  = __builtin_amdgcn_rcpf(fmaf(0.3275911f, az, 1.0f));
  float p  = t * fmaf(t, fmaf(t, fmaf(t, fmaf(t, 1.061405429f, -1.453152027f),
                                      1.421413741f), -0.284496736f), 0.254829592f);
  float e    = __expf(-z * z);
  float erfa = fmaf(-p, e, 1.0f);
  float er   = (z < 0.0f) ? -erfa : erfa;
  return v * fmaf(0.5f, er, 0.5f);
}

// ---------------- merged prep: wb2/out_tail (bb 0-1), W1T (bb 2-17),
// ---------------- W2T w-folded bf16 (bb 18-273). One launch. ---------------
// R6: W1T k-axis PERMUTED to interleave sin/cos rows of the same frequency:
//   fragment element e = 2d   -> W1 row (quad*4 + d)        [sin freq q*4+d]
//   fragment element e = 2d+1 -> W1 row (16 + quad*4 + d)   [cos freq q*4+d]
__global__ __launch_bounds__(256) void k_pre(const float* __restrict__ w_raw,
                                             const float* __restrict__ b2,
                                             const float* __restrict__ W1,
                                             const float* __restrict__ W2,
                                             float* __restrict__ wb2,
                                             float* __restrict__ out_tail,
                                             uint4* __restrict__ W1T,
                                             uint4* __restrict__ W2T) {
  __shared__ float ls[64 * 65];
  int bb = blockIdx.x, tid = threadIdx.x;
  // redundant per-thread softmax (64-wide, cheap)
  float m = -1e30f;
  for (int i = 0; i < F_N; i++) m = fmaxf(m, w_raw[i]);
  float s = 0.f;
  for (int i = 0; i < F_N; i++) s += expf(w_raw[i] - m);
  float inv_s = 1.0f / s;

  if (bb < 2) {
    int e = bb * 256 + tid;
    float a = 0.f;
    for (int f = 0; f < F_N; f++)
      a = fmaf(expf(w_raw[f] - m) * inv_s, b2[f * E_N + e], a);
    wb2[e] = a;
    if (bb == 0 && tid < F_N) out_tail[tid] = expf(w_raw[tid] - m) * inv_s;
  } else if (bb < 18) {
    // W1T[(f*2+jt)*64+lane] = 8 bf16, k-permuted (see header comment)
    int f = (bb - 2) * 4 + (tid >> 6);
    int lane = tid & 63, quad = lane >> 4, r16 = lane & 15;
#pragma unroll
    for (int jt = 0; jt < 2; jt++) {
      union { __hip_bfloat162 p[4]; uint4 u; } pk;
#pragma unroll
      for (int d = 0; d < 4; d++) {
        float lo = W1[f * 1024 + (quad * 4 + d) * 32 + jt * 16 + r16];        // sin
        float hi = W1[f * 1024 + (16 + quad * 4 + d) * 32 + jt * 16 + r16];   // cos
        pk.p[d] = __float22bfloat162_rn(make_float2(lo, hi));
      }
      W1T[(f * 2 + jt) * 64 + lane] = pk.u;
    }
  } else {
    // W2T blocked [k_oct][e][8], rows pre-scaled by softmax w[f=k>>5]
    int blk = bb - 18;
    int kt = blk >> 3, et = blk & 7;
    int k0 = kt * 64, e0 = et * 64;
#pragma unroll
    for (int i = 0; i < 16; i++) {
      int idx = i * 256 + tid;
      int r = idx >> 6, c = idx & 63;
      float wrow = expf(w_raw[(k0 + r) >> 5] - m) * inv_s;
      ls[r * 65 + c] = W2[(size_t)(k0 + r) * E_N + e0 + c] * wrow;
    }
    __syncthreads();
#pragma unroll
    for (int i = 0; i < 2; i++) {
      int t = i * 256 + tid;
      int ko = t >> 6, e = t & 63;
      union { __hip_bfloat162 p[4]; uint4 u; } pk;
#pragma unroll
      for (int d = 0; d < 4; d++)
        pk.p[d] = __float22bfloat162_rn(make_float2(ls[(ko * 8 + 2 * d) * 65 + e],
                                                    ls[(ko * 8 + 2 * d + 1) * 65 + e]));
      W2T[(size_t)(kt * 8 + ko) * E_N + e0 + e] = pk.u;
    }
  }
}

// ---- enc chunk: wave's feature f=c*8+wave -> hwb (blocked [ko][b][8bf16]) --
// xs XOR-swizzled: x(f,b) at xs[f*64 + (b ^ (f&31))].
// sincos: 1 v_sin + 1 v_cos + 3-step angle-doubling (matches permuted W1T).
// BYTE-IDENTICAL to the R10-verified version (209 us, no spill).
__device__ __forceinline__ void enc_chunk(int c, int wave, int lane, int quad,
                                          int r16, const float* xs, uint4* hwb,
                                          const uint4* __restrict__ W1T,
                                          const float* __restrict__ b1,
                                          const float* __restrict__ gamma,
                                          const float* __restrict__ beta,
                                          float c_t) {
  int f = c * 8 + wave;
  bf16x8 a0 = __builtin_bit_cast(bf16x8, W1T[(f * 2 + 0) * 64 + lane]);
  bf16x8 a1 = __builtin_bit_cast(bf16x8, W1T[(f * 2 + 1) * 64 + lane]);
  f32x4 c0, c1;  // seed C with b1 (row j = jt*16 + quad*4 + rr)
  float gv[8], bev[8];
#pragma unroll
  for (int rr = 0; rr < 4; rr++) {
    c0[rr] = b1[f * 32 + quad * 4 + rr];
    c1[rr] = b1[f * 32 + 16 + quad * 4 + rr];
  }
#pragma unroll
  for (int q = 0; q < 8; q++) {
    int idx = f * 32 + (q >> 2) * 16 + quad * 4 + (q & 3);
    gv[q] = gamma[idx];
    bev[q] = beta[idx];
  }
  int swz = f & 31;
#pragma unroll
  for (int bt = 0; bt < 4; bt++) {
    float x = xs[f * 64 + ((bt * 16 + r16) ^ swz)];
    float y = x * c_t;
    y = y - floorf(y);
    float sv = __builtin_amdgcn_sinf(y);
    float cv = __builtin_amdgcn_cosf(y);
    float v[8];
    v[0] = sv; v[1] = cv;
#pragma unroll
    for (int d = 1; d < 4; d++) {
      float c2 = cv + cv;
      float sn = c2 * sv;                 // sin(2t) = 2 sin t cos t
      float cn = fmaf(c2, cv, -1.0f);     // cos(2t) = 2 cos^2 t - 1
      v[2 * d] = sn; v[2 * d + 1] = cn;
      sv = sn; cv = cn;
    }
    union { __hip_bfloat162 p[4]; bf16x8 r; } pk;
#pragma unroll
    for (int d = 0; d < 4; d++)
      pk.p[d] = __float22bfloat162_rn(make_float2(v[2 * d], v[2 * d + 1]));
    f32x4 e0 = __builtin_amdgcn_mfma_f32_16x16x32_bf16(a0, pk.r, c0, 0, 0, 0);
    f32x4 e1 = __builtin_amdgcn_mfma_f32_16x16x32_bf16(a1, pk.r, c1, 0, 0, 0);
    float h[8];
#pragma unroll
    for (int rr = 0; rr < 4; rr++) { h[rr] = e0[rr]; h[4 + rr] = e1[rr]; }
    float sum = 0.f;
#pragma unroll
    for (int q = 0; q < 8; q++) sum += h[q];
    sum += __shfl_xor(sum, 16);
    sum += __shfl_xor(sum, 32);
    float mu = sum * (1.0f / 32.0f);
    float var = 0.f;
#pragma unroll
    for (int q = 0; q < 8; q++) { h[q] -= mu; var = fmaf(h[q], h[q], var); }
    var += __shfl_xor(var, 16);
    var += __shfl_xor(var, 32);
    float rs = __builtin_amdgcn_rsqf(fmaf(var, (1.0f / 32.0f), 1e-5f));
#pragma unroll
    for (int q = 0; q < 8; q++) {
      float hn = fmaf(h[q] * rs, gv[q], bev[q]);
      h[q] = gelu_fast(hn);  // w[f] folded into W2T
    }
    int b_local = bt * 16 + r16;
#pragma unroll
    for (int jt = 0; jt < 2; jt++) {
      union { __hip_bfloat162 p[2]; uint2 u; } pw;
      pw.p[0] = __float22bfloat162_rn(make_float2(h[jt * 4 + 0], h[jt * 4 + 1]));
      pw.p[1] = __float22bfloat162_rn(make_float2(h[jt * 4 + 2], h[jt * 4 + 3]));
      int ko_local = wave * 4 + jt * 2 + (quad >> 1);
      *(uint2*)((char*)hwb + ((size_t)(ko_local * 64 + b_local) * 16 +
                              (quad & 1) * 8)) = pw.u;
    }
  }
}

// ---- gemm chunk: acc += hwb(64b x 256k) @ W2T[c](256k x 64n strip) --------
// BYTE-IDENTICAL to the R10-verified version.
__device__ __forceinline__ void gemm_chunk(int c, int n_base, int quad, int r16,
                                           const uint4* hwb,
                                           const uint4* __restrict__ W2T,
                                           f32x4 (&acc)[4][4]) {
#pragma unroll
  for (int s = 0; s < 8; s++) {
    bf16x8 af[4], bfr[4];
#pragma unroll
    for (int nt = 0; nt < 4; nt++)
      bfr[nt] = __builtin_bit_cast(
          bf16x8, W2T[(size_t)(c * 32 + s * 4 + quad) * E_N + n_base + nt * 16 + r16]);
#pragma unroll
    for (int mt = 0; mt < 4; mt++)
      af[mt] = __builtin_bit_cast(bf16x8, hwb[(s * 4 + quad) * 64 + mt * 16 + r16]);
#pragma unroll
    for (int mt = 0; mt < 4; mt++)
#pragma unroll
      for (int nt = 0; nt < 4; nt++)
        acc[mt][nt] = __builtin_amdgcn_mfma_f32_16x16x32_bf16(af[mt], bfr[nt],
                                                              acc[mt][nt], 0, 0, 0);
  }
}

// ---------------- WAVE-SPECIALIZED producer/consumer -----------------------
// R15: R7/R11/R14 proved merging enc+gemm liveness in ONE instruction stream
// spills (3x, ~0.5-1.5 GB scratch traffic). Wave specialization puts them in
// DISJOINT top-level branches: 16 waves, waves 0-7 = enc producers (EncSt,
// no acc), waves 8-15 = gemm consumers (acc 64 AGPR, no EncSt). Register
// budget = max(paths), not sum. Each SIMD hosts 2 enc + 2 gemm waves ->
// MFMA and VALU pipes run concurrently from different waves (m114).
// Per-wave work identical to R10 (enc: 1 feature/chunk; gemm: 64-col strip).
// Barrier counts match across branches (9 each); same double-buffer rules:
// between bar(k),bar(k+1): enc writes buf(k&1), gemm reads buf(~k&1).
// LDS 81920 -> 1 block/CU x 16 waves = 4 waves/SIMD (same as R10's 2x8).
__global__ __launch_bounds__(1024, 4) void k_fused(const float* __restrict__ bf,
                                                   const uint4* __restrict__ W1T,
                                                   const float* __restrict__ b1,
                                                   const float* __restrict__ gamma,
                                                   const float* __restrict__ beta,
                                                   const uint4* __restrict__ W2T,
                                                   const float* __restrict__ wb2,
                                                   float* __restrict__ out) {
  __shared__ float xs[64 * 64];     // x transposed [f][b^swz], XOR-swizzled
  __shared__ uint4 hwA[32 * 64];    // Hw chunk buffers (32 KB each)
  __shared__ uint4 hwB[32 * 64];
  int tid = threadIdx.x;
  int b0 = blockIdx.x * 64;
#pragma unroll
  for (int i = 0; i < 4; i++) {
    int idx = i * 1024 + tid;
    int f = idx & 63, b = idx >> 6;
    xs[f * 64 + (b ^ (f & 31))] =
        __builtin_nontemporal_load(bf + (size_t)b0 * F_N + idx);
  }
  int wave = tid >> 6, lane = tid & 63;
  int quad = lane >> 4, r16 = lane & 15;
  __syncthreads();  // bar1: xs visible

  if (wave < 8) {
    // ---------------- ENC role (producer) ----------------
    // base angle scale: freq idx quad*4 -> 0.1 * 2^(4*quad) / (2*pi)
    float c_t = 0.015915494309189535f;
    if (quad & 1) c_t *= 16.0f;
    if (quad & 2) c_t *= 256.0f;
    enc_chunk(0, wave, lane, quad, r16, xs, hwA, W1T, b1, gamma, beta, c_t);
    __syncthreads();  // bar2: hwA visible
#pragma unroll
    for (int c = 1; c < 8; ++c) {
      enc_chunk(c, wave, lane, quad, r16, xs, (c & 1) ? hwB : hwA, W1T, b1,
                gamma, beta, c_t);
      __syncthreads();  // bar(c+2)
    }
    // 9 barriers total; done (exited waves auto-release later barriers: none)
  } else {
    // ---------------- GEMM role (consumer) ----------------
    int n_base = (wave - 8) * 64;
    f32x4 acc[4][4];
    f32x4 zero = {0.f, 0.f, 0.f, 0.f};
#pragma unroll
    for (int i = 0; i < 4; i++)
#pragma unroll
      for (int j = 0; j < 4; j++) acc[i][j] = zero;
    __syncthreads();  // bar2: hwA visible
#pragma unroll
    for (int c = 0; c < 7; ++c) {
      gemm_chunk(c, n_base, quad, r16, (c & 1) ? hwB : hwA, W2T, acc);
      __syncthreads();  // bar(c+3)
    }
    gemm_chunk(7, n_base, quad, r16, hwB, W2T, acc);  // no barrier after

    // epilogue: C/D layout col=n (r16), row=m (quad*4+rr); add wb2 bias.
    // nt innermost: 64B line-halves back-to-back; nontemporal (keep W2T in L2)
    float biasv[4];
#pragma unroll
    for (int nt = 0; nt < 4; nt++) biasv[nt] = wb2[n_base + nt * 16 + r16];
#pragma unroll
    for (int mt = 0; mt < 4; mt++) {
#pragma unroll
      for (int rr = 0; rr < 4; rr++) {
        size_t m = (size_t)b0 + mt * 16 + quad * 4 + rr;
        float* orow = out + m * E_N + n_base + r16;
#pragma unroll
        for (int nt = 0; nt < 4; nt++)
          __builtin_nontemporal_store(acc[mt][nt][rr] + biasv[nt], &orow[nt * 16]);
      }
    }
  }
}

// ---------------- correctness fallback if ws_size too small ----------------
__global__ __launch_bounds__(64) void k_naive(const float* __restrict__ bf,
                                              const float* __restrict__ w_raw,
                                              const float* __restrict__ W1,
                                              const float* __restrict__ b1,
                                              const float* __restrict__ gamma,
                                              const float* __restrict__ beta,
                                              const float* __restrict__ W2,
                                              const float* __restrict__ b2,
                                              float* __restrict__ out) {
  int b = blockIdx.x;
  int lane = threadIdx.x;
  float m = -1e30f;
  for (int i = 0; i < F_N; i++) m = fmaxf(m, w_raw[i]);
  float s = 0.f;
  for (int i = 0; i < F_N; i++) s += expf(w_raw[i] - m);
  float inv_s = 1.0f / s;
  float acc[8];
#pragma unroll
  for (int r = 0; r < 8; r++) acc[r] = 0.f;
  __shared__ float hs[32];
  for (int f = 0; f < F_N; f++) {
    float wf = expf(w_raw[f] - m) * inv_s;
    __syncthreads();
    if (lane < 32) {
      float x = bf[(size_t)b * F_N + f];
      float t = x * 0.015915494309189535f;
      float h = b1[f * 32 + lane];
#pragma unroll
      for (int i = 0; i < 16; i++) {
        float y = t - floorf(t);
        h = fmaf(__builtin_amdgcn_sinf(y), W1[f * 1024 + i * 32 + lane], h);
        h = fmaf(__builtin_amdgcn_cosf(y), W1[f * 1024 + 512 + i * 32 + lane], h);
        t = t + t;
      }
      float sum = h;
#pragma unroll
      for (int msk = 1; msk < 32; msk <<= 1) sum += __shfl_xor(sum, msk, 64);
      float mu = sum * (1.0f / 32.0f);
      float d = h - mu;
      float sq = d * d;
#pragma unroll
      for (int msk = 1; msk < 32; msk <<= 1) sq += __shfl_xor(sq, msk, 64);
      float rs = __builtin_amdgcn_rsqf(fmaf(sq, (1.0f / 32.0f), 1e-5f));
      float hn = fmaf(d * rs, gamma[f * 32 + lane], beta[f * 32 + lane]);
      hs[lane] = gelu_exact(hn) * wf;
    }
    __syncthreads();
#pragma unroll
    for (int r = 0; r < 8; r++) {
      int e = r * 64 + lane;
      float a = fmaf(wf, b2[f * E_N + e], acc[r]);
      for (int j = 0; j < 32; j++)
        a = fmaf(hs[j], W2[(size_t)(f * 32 + j) * E_N + e], a);
      acc[r] = a;
    }
  }
#pragma unroll
  for (int r = 0; r < 8; r++) out[(size_t)b * E_N + r * 64 + lane] = acc[r];
  if (b == 0) out[(size_t)B_N * E_N + lane] = expf(w_raw[lane] - m) * inv_s;
}

extern "C" void kernel_launch(void* const* d_in, const int* in_sizes, int n_in,
                              void* d_out, int out_size, void* d_ws, size_t ws_size,
                              hipStream_t stream) {
  const float* bf    = (const float*)d_in[0];
  const float* w_raw = (const float*)d_in[1];
  const float* W1    = (const float*)d_in[2];
  const float* b1    = (const float*)d_in[3];
  const float* gamma = (const float*)d_in[4];
  const float* beta  = (const float*)d_in[5];
  const float* W2    = (const float*)d_in[6];
  const float* b2    = (const float*)d_in[7];
  float* out = (float*)d_out;

  const size_t W2T_BYTES = (size_t)256 * E_N * 16;  // 2 MB
  const size_t W_OFF     = W2T_BYTES;
  const size_t WB2_OFF   = W_OFF + 256;
  const size_t W1T_OFF   = WB2_OFF + 4096;
  const size_t NEED      = W1T_OFF + 131072;

  if (ws_size < NEED) {  // deterministic fallback (correctness insurance)
    k_naive<<<B_N, 64, 0, stream>>>(bf, w_raw, W1, b1, gamma, beta, W2, b2, out);
    return;
  }
  char* ws = (char*)d_ws;
  uint4* W2T = (uint4*)ws;
  float* wb2 = (float*)(ws + WB2_OFF);
  uint4* W1T = (uint4*)(ws + W1T_OFF);

  k_pre<<<274, 256, 0, stream>>>(w_raw, b2, W1, W2, wb2,
                                 out + (size_t)B_N * E_N, W1T, W2T);
  k_fused<<<B_N / 64, 1024, 0, stream>>>(bf, W1T, b1, gamma, beta, W2T, wb2, out);
}